// Round 2
// baseline (172.128 us; speedup 1.0000x reference)
//
#include <hip/hip_runtime.h>
#include <hip/hip_bf16.h>

#define NROWS 131072
#define DK    1024
#define CCLS  21
#define CTF   84
#define NCOL  105         // 21 + 84
#define NKT   (DK/32)     // 32 k-tiles of 32
#define NCT   7           // 112 padded cols / 16
#define BM    128         // rows per block = 4 waves x 32

typedef __attribute__((ext_vector_type(4))) float f32x4;
typedef __attribute__((ext_vector_type(8))) short bf16x8;

__device__ __forceinline__ unsigned short f2bf_rne(float x) {
    union { float f; unsigned u; } v; v.f = x;
    unsigned r = v.u + 0x7fffu + ((v.u >> 16) & 1u);
    return (unsigned short)(r >> 16);
}

// round-half-up pack of two f32 into one u32 of two bf16 (lo in [15:0])
__device__ __forceinline__ unsigned pack2(float lo, float hi) {
    union { float f; unsigned u; } a, b; a.f = lo; b.f = hi;
    return ((a.u + 0x8000u) >> 16) | ((b.u + 0x8000u) & 0xffff0000u);
}

__device__ __forceinline__ bf16x8 cvt8(const f32x4 lo, const f32x4 hi) {
    union { unsigned u[4]; bf16x8 v; } r;
    r.u[0] = pack2(lo[0], lo[1]);
    r.u[1] = pack2(lo[2], lo[3]);
    r.u[2] = pack2(hi[0], hi[1]);
    r.u[3] = pack2(hi[2], hi[3]);
    return r.v;
}

// Pack [W_cls | W_tf | zero-pad] into bf16 MFMA B-fragment order (unchanged,
// verified in round 1): element ((kt*NCT+ct)*64+lane)*8 + j = B[k][col],
// col = ct*16 + (lane&15), k = kt*32 + (lane>>4)*8 + j
__global__ void pack_B_kernel(const float* __restrict__ Wc,
                              const float* __restrict__ Wt,
                              unsigned short* __restrict__ Bp) {
    const int frag = blockIdx.x;           // 224 total
    const int kt = frag / NCT, ct = frag % NCT;
    const int lane = threadIdx.x;          // 64
    const int col = ct * 16 + (lane & 15);
    const int k0  = kt * 32 + ((lane >> 4) << 3);
    bf16x8 o;
#pragma unroll
    for (int j = 0; j < 8; ++j) {
        const int k = k0 + j;
        float v = 0.0f;
        if (col < CCLS)      v = Wc[k * CCLS + col];
        else if (col < NCOL) v = Wt[k * CTF + (col - CCLS)];
        o[j] = (short)f2bf_rne(v);
    }
    *reinterpret_cast<bf16x8*>(Bp + ((size_t)frag * 64 + lane) * 8) = o;
}

// Barrier-free, LDS-free GEMM: each wave owns 32 rows (2 x 16-row MFMA tiles),
// loads its A fragments straight from global f32 (128B-contiguous per row),
// converts in-register, accumulates 2x7 16x16 tiles. Latency hidden by TLP.
__global__ __launch_bounds__(256, 4)
void roi_gemm_kernel(const float* __restrict__ F,
                     const unsigned short* __restrict__ Bp,
                     const float* __restrict__ bcls,
                     const float* __restrict__ btf,
                     float* __restrict__ out) {
    const int t    = threadIdx.x;
    const int wave = t >> 6;
    const int lane = t & 63;
    const int fr   = lane & 15;            // A row within 16-tile / C col
    const int fk   = (lane >> 4) * 8;      // k offset within 32

    const long rw = (long)blockIdx.x * BM + wave * 32;   // wave's first row
    const float* pa0 = F + (size_t)(rw + fr) * DK + fk;  // rt=0 lane base
    const float* pa1 = pa0 + (size_t)16 * DK;            // rt=1

    f32x4 acc[2][NCT];
#pragma unroll
    for (int a = 0; a < 2; ++a)
#pragma unroll
        for (int b = 0; b < NCT; ++b)
            acc[a][b] = (f32x4){0.f, 0.f, 0.f, 0.f};

    const unsigned short* bb = Bp + (size_t)lane * 8;

    for (int kt = 0; kt < NKT; ++kt) {
        // A: 8 f32 per row-tile, 32B/lane, 128B contiguous per row
        const f32x4 a0lo = *reinterpret_cast<const f32x4*>(pa0 + kt * 32);
        const f32x4 a0hi = *reinterpret_cast<const f32x4*>(pa0 + kt * 32 + 4);
        const f32x4 a1lo = *reinterpret_cast<const f32x4*>(pa1 + kt * 32);
        const f32x4 a1hi = *reinterpret_cast<const f32x4*>(pa1 + kt * 32 + 4);

        // B fragments from L2-resident packed buffer, 16B/lane contiguous
        bf16x8 bfrag[NCT];
#pragma unroll
        for (int ct = 0; ct < NCT; ++ct)
            bfrag[ct] = *reinterpret_cast<const bf16x8*>(
                bb + ((size_t)kt * NCT + ct) * 64 * 8);

        const bf16x8 af0 = cvt8(a0lo, a0hi);
        const bf16x8 af1 = cvt8(a1lo, a1hi);

#pragma unroll
        for (int ct = 0; ct < NCT; ++ct) {
            acc[0][ct] = __builtin_amdgcn_mfma_f32_16x16x32_bf16(
                af0, bfrag[ct], acc[0][ct], 0, 0, 0);
            acc[1][ct] = __builtin_amdgcn_mfma_f32_16x16x32_bf16(
                af1, bfrag[ct], acc[1][ct], 0, 0, 0);
        }
    }

    // epilogue: bias + scatter into the two outputs
    float* out_tf = out + (size_t)NROWS * CCLS;
#pragma unroll
    for (int rt = 0; rt < 2; ++rt) {
        const long rbase = rw + rt * 16 + ((lane >> 4) << 2);
#pragma unroll
        for (int ct = 0; ct < NCT; ++ct) {
            const int col = ct * 16 + fr;
            if (col >= NCOL) continue;
            const float bias = (col < CCLS) ? bcls[col] : btf[col - CCLS];
#pragma unroll
            for (int j = 0; j < 4; ++j) {
                const long row = rbase + j;
                const float v = acc[rt][ct][j] + bias;
                if (col < CCLS) out[row * CCLS + col] = v;
                else            out_tf[row * CTF + (col - CCLS)] = v;
            }
        }
    }
}

extern "C" void kernel_launch(void* const* d_in, const int* in_sizes, int n_in,
                              void* d_out, int out_size, void* d_ws, size_t ws_size,
                              hipStream_t stream) {
    const float* F  = (const float*)d_in[0];
    const float* Wc = (const float*)d_in[1];
    const float* bc = (const float*)d_in[2];
    const float* Wt = (const float*)d_in[3];
    const float* bt = (const float*)d_in[4];
    unsigned short* Bp = (unsigned short*)d_ws;   // 229,376 B

    pack_B_kernel<<<NKT * NCT, 64, 0, stream>>>(Wc, Wt, Bp);
    roi_gemm_kernel<<<NROWS / BM, 256, 0, stream>>>(F, Bp, bc, bt, (float*)d_out);
}